// Round 1
// baseline (145.786 us; speedup 1.0000x reference)
//
#include <hip/hip_runtime.h>
#include <math.h>

// Problem geometry (fixed by reference):
//   x: (T=32, B=8, C=64, H=64, W=64) fp32, contiguous.
//   SLICE = C*H*W = 262144 elements per (t,b) slice.
//   TB = T*B = 256 slices.
#define SLICE 262144
#define TBCNT 256

// ---------------------------------------------------------------------------
// Kernel 1: per-(t,b) slice sum. One 1024-thread block per slice (256 blocks).
// Each thread reads 64 float4 (contiguous, fully coalesced).
// ---------------------------------------------------------------------------
__global__ __launch_bounds__(1024) void se_sum_kernel(const float* __restrict__ x,
                                                      float* __restrict__ sums) {
    const int slice = blockIdx.x;  // == t*8 + b
    const float4* xp = (const float4*)(x + (size_t)slice * SLICE);
    const int tid = threadIdx.x;

    float acc = 0.0f;
#pragma unroll
    for (int k = 0; k < SLICE / 4 / 1024; ++k) {  // 64 iterations
        float4 v = xp[tid + k * 1024];
        acc += (v.x + v.y) + (v.z + v.w);
    }

    // wave (64-lane) shuffle reduce
    for (int off = 32; off > 0; off >>= 1)
        acc += __shfl_down(acc, off, 64);

    __shared__ float lds[16];
    const int lane = tid & 63;
    const int wave = tid >> 6;
    if (lane == 0) lds[wave] = acc;
    __syncthreads();
    if (tid == 0) {
        float s = 0.0f;
#pragma unroll
        for (int w = 0; w < 16; ++w) s += lds[w];
        sums[slice] = s;
    }
}

// ---------------------------------------------------------------------------
// Kernel 2: tiny excite MLP. Single block, 256 threads.
//   mean (T,B) -> h[b][j] = relu(sum_t mean[t][b] * w1[j][t])   (w1: (32,32))
//             -> d[b][t] = sigmoid(sum_j h[b][j] * w2[t][j])    (w2: (32,32))
//   scale[t*8+b] = d[b][t]
// ---------------------------------------------------------------------------
__global__ __launch_bounds__(256) void se_mlp_kernel(const float* __restrict__ sums,
                                                     const float* __restrict__ w1,
                                                     const float* __restrict__ w2,
                                                     float* __restrict__ scale) {
    __shared__ float smean[TBCNT];  // [t*8+b]
    __shared__ float h[8][32];      // [b][j]
    const int tid = threadIdx.x;

    smean[tid] = sums[tid] * (1.0f / (float)SLICE);
    __syncthreads();

    const int b = tid >> 5;
    const int j = tid & 31;
    float a = 0.0f;
#pragma unroll
    for (int t = 0; t < 32; ++t) a += smean[t * 8 + b] * w1[j * 32 + t];
    h[b][j] = fmaxf(a, 0.0f);
    __syncthreads();

    const int t = tid & 31;
    float v = 0.0f;
#pragma unroll
    for (int jj = 0; jj < 32; ++jj) v += h[b][jj] * w2[t * 32 + jj];
    scale[t * 8 + b] = 1.0f / (1.0f + expf(-v));
}

// ---------------------------------------------------------------------------
// Kernel 3: out = scale[t,b] * x. One float4 per thread.
// elem index = i4*4; slice index = elem >> 18 == i4 >> 16 (uniform per block,
// since each 256-thread block covers 1024 contiguous elements).
// ---------------------------------------------------------------------------
__global__ __launch_bounds__(256) void se_scale_kernel(const float* __restrict__ x,
                                                       const float* __restrict__ scale,
                                                       float* __restrict__ out) {
    const size_t i4 = (size_t)blockIdx.x * 256 + threadIdx.x;
    const int tb = (int)(i4 >> 16);
    const float s = scale[tb];
    float4 v = ((const float4*)x)[i4];
    v.x *= s; v.y *= s; v.z *= s; v.w *= s;
    ((float4*)out)[i4] = v;
}

extern "C" void kernel_launch(void* const* d_in, const int* in_sizes, int n_in,
                              void* d_out, int out_size, void* d_ws, size_t ws_size,
                              hipStream_t stream) {
    const float* x  = (const float*)d_in[0];
    const float* w1 = (const float*)d_in[1];
    const float* w2 = (const float*)d_in[2];
    float* out = (float*)d_out;

    float* ws_sums  = (float*)d_ws;          // 256 floats
    float* ws_scale = ws_sums + TBCNT;       // 256 floats

    se_sum_kernel<<<TBCNT, 1024, 0, stream>>>(x, ws_sums);
    se_mlp_kernel<<<1, 256, 0, stream>>>(ws_sums, w1, w2, ws_scale);

    const size_t total4 = (size_t)TBCNT * SLICE / 4;  // 16,777,216 float4
    se_scale_kernel<<<(int)(total4 / 256), 256, 0, stream>>>(x, ws_scale, out);
}

// Round 3
// 122.625 us; speedup vs baseline: 1.1889x; 1.1889x over previous
//
#include <hip/hip_runtime.h>
#include <math.h>

// Geometry (fixed): x (T=32, B=8, C=64, H=64, W=64) fp32 contiguous.
// SLICE = C*H*W = 262144 elem per (t,b) slice; TB = 256 slices.
// Total = 64 Mi elements = 256 MiB.
#define SLICE 262144
#define TBCNT 256
#define NPART 8                     // partial sums per slice
#define SUMBLOCKS (TBCNT * NPART)   // 2048 blocks

typedef float f32x4 __attribute__((ext_vector_type(4)));  // clang vector: OK for nontemporal builtins

// ---------------------------------------------------------------------------
// Kernel 1: partial sums. 2048 blocks x 256 threads (8 blocks/CU, 32 waves/CU).
// Block i handles chunk (i & 7) of slice (i >> 3): 32768 contiguous floats.
// Deterministic: each block writes its own partial; no atomics.
// ---------------------------------------------------------------------------
__global__ __launch_bounds__(256) void se_sum_kernel(const float* __restrict__ x,
                                                     float* __restrict__ partial) {
    const int bid = blockIdx.x;
    const int tid = threadIdx.x;
    const f32x4* xp = (const f32x4*)x + (size_t)bid * 8192;  // 8192 float4 / block

    float acc = 0.0f;
#pragma unroll
    for (int k = 0; k < 32; ++k) {
        f32x4 v = xp[tid + k * 256];
        acc += (v.x + v.y) + (v.z + v.w);
    }

    // 64-lane wave shuffle reduce
    for (int off = 32; off > 0; off >>= 1)
        acc += __shfl_down(acc, off, 64);

    __shared__ float lds[4];
    if ((tid & 63) == 0) lds[tid >> 6] = acc;
    __syncthreads();
    if (tid == 0) partial[bid] = (lds[0] + lds[1]) + (lds[2] + lds[3]);
}

// ---------------------------------------------------------------------------
// Kernel 2: finish sums (fixed order -> deterministic) + tiny excite MLP.
//   mean (T,B) -> h[b][j] = relu(sum_t mean[t][b] * w1[j][t])   (w1: (32,32))
//             -> d[b][t] = sigmoid(sum_j h[b][j] * w2[t][j])    (w2: (32,32))
//   scale[t*8+b] = d[b][t]
// ---------------------------------------------------------------------------
__global__ __launch_bounds__(256) void se_mlp_kernel(const float* __restrict__ partial,
                                                     const float* __restrict__ w1,
                                                     const float* __restrict__ w2,
                                                     float* __restrict__ scale) {
    __shared__ float smean[TBCNT];  // [t*8+b]
    __shared__ float h[8][32];      // [b][j]
    const int tid = threadIdx.x;

    float s = 0.0f;
#pragma unroll
    for (int k = 0; k < NPART; ++k) s += partial[tid * NPART + k];
    smean[tid] = s * (1.0f / (float)SLICE);
    __syncthreads();

    const int b = tid >> 5;
    const int j = tid & 31;
    float a = 0.0f;
#pragma unroll
    for (int t = 0; t < 32; ++t) a += smean[t * 8 + b] * w1[j * 32 + t];
    h[b][j] = fmaxf(a, 0.0f);
    __syncthreads();

    const int t = tid & 31;
    float v = 0.0f;
#pragma unroll
    for (int jj = 0; jj < 32; ++jj) v += h[b][jj] * w2[t * 32 + jj];
    scale[t * 8 + b] = 1.0f / (1.0f + expf(-v));
}

// ---------------------------------------------------------------------------
// Kernel 3: out = scale[t,b] * x. 2 float4 per thread; nontemporal stores so
// the write stream doesn't evict x from L3 (x was just pulled in by kernel 1,
// and 256 MiB = exactly L3 capacity). Slice idx uniform per block:
// block covers 2048 contiguous floats, slice = 262144 floats.
// ---------------------------------------------------------------------------
__global__ __launch_bounds__(256) void se_scale_kernel(const float* __restrict__ x,
                                                       const float* __restrict__ scale,
                                                       float* __restrict__ out) {
    const size_t base = (size_t)blockIdx.x * 512;   // float4 index
    const int tb = (int)(base >> 16);               // (base*4) >> 18
    const float s = scale[tb];
    const f32x4* xp = (const f32x4*)x;
    f32x4* op = (f32x4*)out;

    size_t i = base + threadIdx.x;
    f32x4 v = xp[i];
    v *= s;
    __builtin_nontemporal_store(v, &op[i]);

    size_t j = i + 256;
    f32x4 u = xp[j];
    u *= s;
    __builtin_nontemporal_store(u, &op[j]);
}

extern "C" void kernel_launch(void* const* d_in, const int* in_sizes, int n_in,
                              void* d_out, int out_size, void* d_ws, size_t ws_size,
                              hipStream_t stream) {
    const float* x  = (const float*)d_in[0];
    const float* w1 = (const float*)d_in[1];
    const float* w2 = (const float*)d_in[2];
    float* out = (float*)d_out;

    float* ws_partial = (float*)d_ws;              // 2048 floats
    float* ws_scale   = ws_partial + SUMBLOCKS;    // 256 floats

    se_sum_kernel<<<SUMBLOCKS, 256, 0, stream>>>(x, ws_partial);
    se_mlp_kernel<<<1, 256, 0, stream>>>(ws_partial, w1, w2, ws_scale);

    const size_t total4 = (size_t)TBCNT * SLICE / 4;        // 16,777,216 float4
    se_scale_kernel<<<(int)(total4 / 512), 256, 0, stream>>>(x, ws_scale, out);
}

// Round 4
// 121.993 us; speedup vs baseline: 1.1950x; 1.0052x over previous
//
#include <hip/hip_runtime.h>
#include <math.h>

// Geometry (fixed): x (T=32, B=8, C=64, H=64, W=64) fp32 contiguous.
// SLICE = C*H*W = 262144 elem per (t,b) slice; TB = 256 slices.
// Total = 64 Mi elements = 256 MiB (== L3 capacity).
#define SLICE 262144
#define TBCNT 256
#define NPART 8                     // partial sums per slice
#define SUMBLOCKS (TBCNT * NPART)   // 2048 blocks

typedef float f32x4 __attribute__((ext_vector_type(4)));

// ---------------------------------------------------------------------------
// Kernel 1: partial sums. 2048 blocks x 256 threads (8 blocks/CU, 32 waves/CU).
// Reads x FORWARD -> after completion, L3 holds x with LRU age == address order.
// ---------------------------------------------------------------------------
__global__ __launch_bounds__(256) void se_sum_kernel(const float* __restrict__ x,
                                                     float* __restrict__ partial) {
    const int bid = blockIdx.x;
    const int tid = threadIdx.x;
    const f32x4* xp = (const f32x4*)x + (size_t)bid * 8192;  // 8192 float4 / block

    float acc = 0.0f;
#pragma unroll
    for (int k = 0; k < 32; ++k) {
        f32x4 v = xp[tid + k * 256];
        acc += (v.x + v.y) + (v.z + v.w);
    }

    for (int off = 32; off > 0; off >>= 1)
        acc += __shfl_down(acc, off, 64);

    __shared__ float lds[4];
    if ((tid & 63) == 0) lds[tid >> 6] = acc;
    __syncthreads();
    if (tid == 0) partial[bid] = (lds[0] + lds[1]) + (lds[2] + lds[3]);
}

// ---------------------------------------------------------------------------
// Kernel 2: finish sums (fixed order -> deterministic) + tiny excite MLP.
// ---------------------------------------------------------------------------
__global__ __launch_bounds__(256) void se_mlp_kernel(const float* __restrict__ partial,
                                                     const float* __restrict__ w1,
                                                     const float* __restrict__ w2,
                                                     float* __restrict__ scale) {
    __shared__ float smean[TBCNT];  // [t*8+b]
    __shared__ float h[8][32];      // [b][j]
    const int tid = threadIdx.x;

    float s = 0.0f;
#pragma unroll
    for (int k = 0; k < NPART; ++k) s += partial[tid * NPART + k];
    smean[tid] = s * (1.0f / (float)SLICE);
    __syncthreads();

    const int b = tid >> 5;
    const int j = tid & 31;
    float a = 0.0f;
#pragma unroll
    for (int t = 0; t < 32; ++t) a += smean[t * 8 + b] * w1[j * 32 + t];
    h[b][j] = fmaxf(a, 0.0f);
    __syncthreads();

    const int t = tid & 31;
    float v = 0.0f;
#pragma unroll
    for (int jj = 0; jj < 32; ++jj) v += h[b][jj] * w2[t * 32 + jj];
    scale[t * 8 + b] = 1.0f / (1.0f + expf(-v));
}

// ---------------------------------------------------------------------------
// Kernel 3: out = scale[t,b] * x, processed in REVERSE address order.
// x is L3-resident from kernel 1 (forward order). Reverse reads start at the
// MRU end; write-evictions consume the LRU (front) end -> under LRU, the first
// ~half of the reads hit L3 before the fronts collide. nt-stores to keep the
// write stream out of L1/L2.
// ---------------------------------------------------------------------------
__global__ __launch_bounds__(256) void se_scale_kernel(const float* __restrict__ x,
                                                       const float* __restrict__ scale,
                                                       float* __restrict__ out,
                                                       int nblocks) {
    const int rb = nblocks - 1 - blockIdx.x;        // reversed chunk index
    const size_t base = (size_t)rb * 512;           // float4 index
    const int tb = (int)(base >> 16);               // (base*4) >> 18, uniform per block
    const float s = scale[tb];
    const f32x4* xp = (const f32x4*)x;
    f32x4* op = (f32x4*)out;

    size_t i = base + threadIdx.x;
    f32x4 v = xp[i];
    v *= s;
    __builtin_nontemporal_store(v, &op[i]);

    size_t j = i + 256;
    f32x4 u = xp[j];
    u *= s;
    __builtin_nontemporal_store(u, &op[j]);
}

extern "C" void kernel_launch(void* const* d_in, const int* in_sizes, int n_in,
                              void* d_out, int out_size, void* d_ws, size_t ws_size,
                              hipStream_t stream) {
    const float* x  = (const float*)d_in[0];
    const float* w1 = (const float*)d_in[1];
    const float* w2 = (const float*)d_in[2];
    float* out = (float*)d_out;

    float* ws_partial = (float*)d_ws;              // 2048 floats
    float* ws_scale   = ws_partial + SUMBLOCKS;    // 256 floats

    se_sum_kernel<<<SUMBLOCKS, 256, 0, stream>>>(x, ws_partial);
    se_mlp_kernel<<<1, 256, 0, stream>>>(ws_partial, w1, w2, ws_scale);

    const size_t total4 = (size_t)TBCNT * SLICE / 4;        // 16,777,216 float4
    const int nblocks = (int)(total4 / 512);                // 32768
    se_scale_kernel<<<nblocks, 256, 0, stream>>>(x, ws_scale, out, nblocks);
}